// Round 7
// baseline (791.045 us; speedup 1.0000x reference)
//
#include <hip/hip_runtime.h>

#define BATCH 4096
#define TT 512
#define HH 64
#define XS 516     // x_s row stride in floats
#define HS 72      // h row stride in bf16 (2-way bank aliasing = free)

typedef __attribute__((ext_vector_type(8))) short short8;
typedef __attribute__((ext_vector_type(4))) float floatx4;

__device__ __forceinline__ unsigned short f2bf(float f) {   // RNE f32->bf16
    unsigned u = __float_as_uint(f);
    u = u + 0x7FFFu + ((u >> 16) & 1u);
    return (unsigned short)(u >> 16);
}

// Sync-free design: each wave owns ALL 256 gates for 4 batch rows (x2 streams),
// so h never crosses waves -> zero barriers/flags in the 512-step loop (the
// R1-R6 invariant 1250-1450 cyc/step was the inter-wave exchange chain).
// Batch j sits at MFMA tile row 4j: lane (q,c)'s valid C/D slot is r=0 and it
// holds all 4 gate types of cells (batch q, n=16s+c) at tiles {s,s+4,s+8,s+12}.
// Two independent 4-row streams per wave interleave so stream B's 32 MFMAs
// grind while stream A activates (matrix pipe stays full). Block = 2 waves
// (16 rows), grid 256 = 1 block/CU, 1 wave/SIMD, ~340 VGPRs.
__global__ __launch_bounds__(128, 1) void lstm_kernel(
    const float* __restrict__ x, const float* __restrict__ W_ih,
    const float* __restrict__ W_hh, const float* __restrict__ b_ih,
    const float* __restrict__ b_hh, const float* __restrict__ W_out,
    const float* __restrict__ b_out, float* __restrict__ out)
{
    __shared__ __align__(16) float x_s[16 * XS];                 // 33 KB
    __shared__ __align__(16) unsigned short hls[2][2][16 * HS];  // [wave][stream], rows m%4!=0 stay 0
    __shared__ __align__(16) float hf[16 * 65];

    const int tid = threadIdx.x;
    const int w = tid >> 6;       // wave 0..1
    const int l = tid & 63;
    const int q = l >> 4;
    const int c = l & 15;
    const int bbase = blockIdx.x * 16;

    // stage x[bbase..bbase+15][0..511] into LDS, coalesced float4
    for (int i = 0; i < 16; ++i) {
        int flat = i * 128 + tid;              // 2048 float4s
        int row = flat >> 7, c4 = flat & 127;
        const float4* xg = reinterpret_cast<const float4*>(x + (size_t)(bbase + row) * TT);
        float4 v = xg[c4];
        *reinterpret_cast<float4*>(&x_s[row * XS + c4 * 4]) = v;
    }
    for (int i = tid; i < 2 * 2 * 16 * HS; i += 128)
        (&hls[0][0][0])[i] = 0;                // h0 = 0 + garbage rows stay 0

    // per-lane weights: lane (q,c) covers gates G = 16t + c, t=0..15
    float wih[16], bb[16];
    short8 bfr[16][2];
    #pragma unroll
    for (int t = 0; t < 16; ++t) {
        int g = 16 * t + c;
        wih[t] = W_ih[g];
        bb[t] = b_ih[g] + b_hh[g];
        #pragma unroll
        for (int ks = 0; ks < 2; ++ks) {
            const float* wp = W_hh + g * 64 + ks * 32 + q * 8;
            short8 v;
            #pragma unroll
            for (int j = 0; j < 8; ++j) v[j] = (short)f2bf(wp[j]);
            bfr[t][ks] = v;
        }
    }

    floatx4 accA[16], accB[16];
    #pragma unroll
    for (int t = 0; t < 16; ++t) { accA[t] = floatx4{0.f,0.f,0.f,0.f}; accB[t] = floatx4{0.f,0.f,0.f,0.f}; }
    float cstA[4] = {0,0,0,0}, cstB[4] = {0,0,0,0};
    float hvA[4], hvB[4];

    unsigned short* hA = hls[w][0];
    unsigned short* hB = hls[w][1];
    const int aoff = c * HS + q * 8;       // A-frag offset (shorts)
    const int woff = 4 * q * HS + c;       // h write base: row 4q, + 16s
    const float* xrowA = &x_s[(8 * w + q) * XS];      // stream A batch = bbase+8w+q
    const float* xrowB = &x_s[(8 * w + 4 + q) * XS];  // stream B batch = bbase+8w+4+q
    const float L1 = 1.44269504089f;       // log2(e)
    const float L2 = 2.88539008178f;       // 2*log2(e)

    __syncthreads();   // staging + zeroed h visible (only barrier before head)

    // one stream's matmul for step k: read A-frags (same-wave LDS, lgkm only),
    // init r=0 slots with x_proj, 32 MFMAs cell-grouped
    auto mfma_step = [&](floatx4* acc, const unsigned short* hbuf, float xv) {
        short8 a0 = *reinterpret_cast<const short8*>(hbuf + aoff);
        short8 a1 = *reinterpret_cast<const short8*>(hbuf + aoff + 32);
        #pragma unroll
        for (int t = 0; t < 16; ++t) acc[t][0] = fmaf(xv, wih[t], bb[t]);
        #pragma unroll
        for (int t = 0; t < 16; ++t) {
            acc[t] = __builtin_amdgcn_mfma_f32_16x16x32_bf16(a0, bfr[t][0], acc[t], 0, 0, 0);
            acc[t] = __builtin_amdgcn_mfma_f32_16x16x32_bf16(a1, bfr[t][1], acc[t], 0, 0, 0);
        }
    };
    // one stream's activations: 4 cells/lane (batch q, n=16s+c), R5 5-trans math
    auto act_step = [&](floatx4* acc, float* cst, float* hv, unsigned short* hbuf) {
        #pragma unroll
        for (int s = 0; s < 4; ++s) {
            float gi = acc[s][0], gf = acc[4 + s][0], gg = acc[8 + s][0], go = acc[12 + s][0];
            float ei = __builtin_amdgcn_exp2f(-L1 * gi);
            float ef = __builtin_amdgcn_exp2f(-L1 * gf);
            float eg = __builtin_amdgcn_exp2f( L2 * gg);
            float eo = __builtin_amdgcn_exp2f(-L1 * go);
            float pf1 = 1.f + ef, pig = (1.f + ei) * (1.f + eg);
            float num = fmaf(cst[s], pig, (eg - 1.f) * pf1);
            cst[s] = num * __builtin_amdgcn_rcpf(pf1 * pig);
            float ec = __builtin_amdgcn_exp2f(L2 * cst[s]);
            float h = (ec - 1.f) * __builtin_amdgcn_rcpf((1.f + eo) * (1.f + ec));
            hv[s] = h;
            hbuf[woff + 16 * s] = f2bf(h);
        }
    };

    // software pipeline: B computes step k while A activates step k, and vice versa
    mfma_step(accA, hA, xrowA[0]);
    for (int k = 0; k < TT - 1; ++k) {
        mfma_step(accB, hB, xrowB[k]);
        act_step(accA, cstA, hvA, hA);
        mfma_step(accA, hA, xrowA[k + 1]);
        act_step(accB, cstB, hvB, hB);
    }
    mfma_step(accB, hB, xrowB[TT - 1]);
    act_step(accA, cstA, hvA, hA);
    act_step(accB, cstB, hvB, hB);

    #pragma unroll
    for (int s = 0; s < 4; ++s) {
        hf[(8 * w + q) * 65 + 16 * s + c] = hvA[s];
        hf[(8 * w + 4 + q) * 65 + 16 * s + c] = hvB[s];
    }
    __syncthreads();

    // head: out[b][o] = sum_n hf[b][n]*W_out[o][n] + b_out[o]
    if (tid < 16 * 3) {
        int row = tid / 3, o = tid % 3;
        float s = b_out[o];
        #pragma unroll 8
        for (int k = 0; k < HH; ++k) s = fmaf(hf[row * 65 + k], W_out[o * 64 + k], s);
        out[(size_t)(bbase + row) * 3 + o] = s;
    }
}

extern "C" void kernel_launch(void* const* d_in, const int* in_sizes, int n_in,
                              void* d_out, int out_size, void* d_ws, size_t ws_size,
                              hipStream_t stream) {
    const float* x     = (const float*)d_in[0];
    const float* W_ih  = (const float*)d_in[1];
    const float* W_hh  = (const float*)d_in[2];
    const float* b_ih  = (const float*)d_in[3];
    const float* b_hh  = (const float*)d_in[4];
    const float* W_out = (const float*)d_in[5];
    const float* b_out = (const float*)d_in[6];
    float* out = (float*)d_out;
    hipLaunchKernelGGL(lstm_kernel, dim3(BATCH / 16), dim3(128), 0, stream,
                       x, W_ih, W_hh, b_ih, b_hh, W_out, b_out, out);
}

// Round 8
// 435.821 us; speedup vs baseline: 1.8151x; 1.8151x over previous
//
#include <hip/hip_runtime.h>

#define BATCH 4096
#define TT 512
#define HH 64
#define XS 516     // x_s row stride in floats
#define HS 72      // h row stride in bf16 (conflict-free b128 A-reads)

typedef __attribute__((ext_vector_type(8))) short short8;
typedef __attribute__((ext_vector_type(4))) float floatx4;

__device__ __forceinline__ unsigned short f2bf(float f) {   // RNE f32->bf16
    unsigned u = __float_as_uint(f);
    u = u + 0x7FFFu + ((u >> 16) & 1u);
    return (unsigned short)(u >> 16);
}

// Sync-free, single-wave blocks: 1 wave owns 4 batch rows x all 256 gates, so h
// never leaves the wave (LDS round-trip, same-wave DS ordering, ZERO barriers).
// R7's failure was dual-stream register bloat (AGPR moves) + believing a wave
// can overlap its own MFMA with VALU (it can't — MFMA blocks its wave); this is
// the single-stream repair. Batch j at MFMA tile row 4j: lane (q,c)'s slot r=0
// of tile t = (batch q, gate 16t+c); lane activates cells (batch q, n=16s+c),
// s=0..3 (i,f,g,o at tiles s,s+4,s+8,s+12) — perfectly lane-balanced.
// Block=64 threads -> __launch_bounds__(64,1) allows ~512 VGPRs, no spill.
__global__ __launch_bounds__(64, 1) void lstm_kernel(
    const float* __restrict__ x, const float* __restrict__ W_ih,
    const float* __restrict__ W_hh, const float* __restrict__ b_ih,
    const float* __restrict__ b_hh, const float* __restrict__ W_out,
    const float* __restrict__ b_out, float* __restrict__ out)
{
    __shared__ __align__(16) float x_s[4 * XS];              // 8.25 KB
    __shared__ __align__(16) unsigned short hl[16 * HS];     // rows m%4!=0 stay 0
    __shared__ __align__(16) float hf[4 * 65];

    const int tid = threadIdx.x;   // one wave
    const int q = tid >> 4;        // lane's batch row (0..3)
    const int c = tid & 15;
    const int bbase = blockIdx.x * 4;

    // stage x[bbase..bbase+3][0..511] into LDS (512 float4s, 8 iters)
    for (int i = 0; i < 8; ++i) {
        int flat = i * 64 + tid;
        int row = flat >> 7, c4 = flat & 127;
        const float4* xg = reinterpret_cast<const float4*>(x + (size_t)(bbase + row) * TT);
        float4 v = xg[c4];
        *reinterpret_cast<float4*>(&x_s[row * XS + c4 * 4]) = v;
    }
    for (int i = tid; i < 16 * HS; i += 64) hl[i] = 0;   // h0 = 0, garbage rows stay 0

    // per-lane weights: lane (q,c) covers gates g = 16t + c, t=0..15
    float wih[16], bb[16];
    short8 bfr[16][2];
    #pragma unroll
    for (int t = 0; t < 16; ++t) {
        int g = 16 * t + c;
        wih[t] = W_ih[g];
        bb[t] = b_ih[g] + b_hh[g];
        #pragma unroll
        for (int ks = 0; ks < 2; ++ks) {
            const float4* wp = reinterpret_cast<const float4*>(W_hh + g * 64 + ks * 32 + q * 8);
            float4 w0 = wp[0], w1 = wp[1];
            short8 v;
            v[0] = (short)f2bf(w0.x); v[1] = (short)f2bf(w0.y);
            v[2] = (short)f2bf(w0.z); v[3] = (short)f2bf(w0.w);
            v[4] = (short)f2bf(w1.x); v[5] = (short)f2bf(w1.y);
            v[6] = (short)f2bf(w1.z); v[7] = (short)f2bf(w1.w);
            bfr[t][ks] = v;
        }
    }

    floatx4 acc[16];               // slots r=1..3 face zero A-rows: init once, stay 0
    #pragma unroll
    for (int t = 0; t < 16; ++t) acc[t] = floatx4{0.f, 0.f, 0.f, 0.f};
    float cst[4] = {0.f, 0.f, 0.f, 0.f};
    float hv[4];

    const int aoff = c * HS + q * 8;      // A-frag offset (shorts)
    const int woff = (4 * q) * HS + c;    // h write base (+16s)
    const float* xrow = &x_s[q * XS];
    const float L1 = 1.44269504089f;      // log2(e)
    const float L2 = 2.88539008178f;      // 2*log2(e)

    // no barrier: single wave, DS ops are in-order within the wave
    for (int ts4 = 0; ts4 < TT; ts4 += 4) {
        float4 xq = *reinterpret_cast<const float4*>(xrow + ts4);
        #pragma unroll
        for (int u = 0; u < 4; ++u) {
            short8 a0 = *reinterpret_cast<const short8*>(hl + aoff);
            short8 a1 = *reinterpret_cast<const short8*>(hl + aoff + 32);

            float xv = (&xq.x)[u];
            #pragma unroll
            for (int t = 0; t < 16; ++t) acc[t][0] = fmaf(xv, wih[t], bb[t]);

            #pragma unroll
            for (int t = 0; t < 16; ++t) {
                acc[t] = __builtin_amdgcn_mfma_f32_16x16x32_bf16(a0, bfr[t][0], acc[t], 0, 0, 0);
                acc[t] = __builtin_amdgcn_mfma_f32_16x16x32_bf16(a1, bfr[t][1], acc[t], 0, 0, 0);
            }

            #pragma unroll
            for (int s = 0; s < 4; ++s) {
                float gi = acc[s][0], gf = acc[4 + s][0], gg = acc[8 + s][0], go = acc[12 + s][0];
                float ei = __builtin_amdgcn_exp2f(-L1 * gi);
                float ef = __builtin_amdgcn_exp2f(-L1 * gf);
                float eg = __builtin_amdgcn_exp2f( L2 * gg);
                float eo = __builtin_amdgcn_exp2f(-L1 * go);
                float pf1 = 1.f + ef, pig = (1.f + ei) * (1.f + eg);
                float num = fmaf(cst[s], pig, (eg - 1.f) * pf1);
                cst[s] = num * __builtin_amdgcn_rcpf(pf1 * pig);
                float ec = __builtin_amdgcn_exp2f(L2 * cst[s]);
                float h = (ec - 1.f) * __builtin_amdgcn_rcpf((1.f + eo) * (1.f + ec));
                hv[s] = h;
                hl[woff + 16 * s] = f2bf(h);
            }
        }
    }

    // head: lane-local h -> LDS, then 12 lanes do the 3-wide dot
    #pragma unroll
    for (int s = 0; s < 4; ++s) hf[q * 65 + 16 * s + c] = hv[s];
    if (tid < 4 * 3) {
        int row = tid / 3, o = tid % 3;
        float sum = b_out[o];
        #pragma unroll 8
        for (int k = 0; k < HH; ++k) sum = fmaf(hf[row * 65 + k], W_out[o * 64 + k], sum);
        out[(size_t)(bbase + row) * 3 + o] = sum;
    }
}

extern "C" void kernel_launch(void* const* d_in, const int* in_sizes, int n_in,
                              void* d_out, int out_size, void* d_ws, size_t ws_size,
                              hipStream_t stream) {
    const float* x     = (const float*)d_in[0];
    const float* W_ih  = (const float*)d_in[1];
    const float* W_hh  = (const float*)d_in[2];
    const float* b_ih  = (const float*)d_in[3];
    const float* b_hh  = (const float*)d_in[4];
    const float* W_out = (const float*)d_in[5];
    const float* b_out = (const float*)d_in[6];
    float* out = (float*)d_out;
    hipLaunchKernelGGL(lstm_kernel, dim3(BATCH / 4), dim3(64), 0, stream,
                       x, W_ih, W_hh, b_ih, b_hh, W_out, b_out, out);
}

// Round 9
// 294.090 us; speedup vs baseline: 2.6898x; 1.4819x over previous
//
#include <hip/hip_runtime.h>

#define BATCH 4096
#define TT 512
#define HH 64
#define BT 8       // batch rows per block; batch j at tile row 4*(j>>1)+(j&1) -> valid C/D slots r=0,1
#define XS 516     // x_s row stride in floats
#define HS 72      // h buffer row stride in bf16

typedef __attribute__((ext_vector_type(8))) short short8;
typedef __attribute__((ext_vector_type(4))) float floatx4;

__device__ __forceinline__ unsigned short f2bf(float f) {   // RNE f32->bf16
    unsigned u = __float_as_uint(f);
    u = u + 0x7FFFu + ((u >> 16) & 1u);
    return (unsigned short)(u >> 16);
}

// Best-of-all-rounds combo. Layout = R3 (BT=8, 512 blocks = 2 independent
// blocks/CU -> 2 uncorrelated waves/SIMD; wall was chain-bound at 1243 cyc/step
// with only 2x MFMA duplication). Activations = R5 (5 exp + 2 rcp per cell).
// Extras: persistent zero acc slots r=2,3 (no per-step re-zero), float4 x
// prefetch (1 LDS read / 4 steps / row), register-carried final h (no per-step
// tail check), hoisted LDS offsets. Per-SIMD issue ~570 cyc/step << chain, so
// wall should drop toward the chain floor with stalls filled by the sibling block.
__global__ __launch_bounds__(256, 2) void lstm_kernel(
    const float* __restrict__ x, const float* __restrict__ W_ih,
    const float* __restrict__ W_hh, const float* __restrict__ b_ih,
    const float* __restrict__ b_hh, const float* __restrict__ W_out,
    const float* __restrict__ b_out, float* __restrict__ out)
{
    __shared__ __align__(16) float x_s[BT * XS];             // 16.5 KB
    __shared__ __align__(16) unsigned short hb0[16 * HS];    // h_k, k even; rows m&2 stay 0
    __shared__ __align__(16) unsigned short hb1[16 * HS];    // h_k, k odd
    __shared__ __align__(16) float hf[BT * 65];

    const int tid = threadIdx.x;
    const int w = tid >> 6;       // wave 0..3 -> gate col-tiles {w,w+4,w+8,w+12}
    const int l = tid & 63;
    const int q = l >> 4;
    const int c = l & 15;
    const int n = 16 * w + c;     // hidden index this lane activates
    const int bbase = blockIdx.x * BT;

    // stage x[bbase..bbase+7][0..511] into LDS, coalesced float4
    for (int i = 0; i < 4; ++i) {
        int flat = i * 256 + tid;              // 1024 float4s
        int row = flat >> 7, c4 = flat & 127;
        const float4* xg = reinterpret_cast<const float4*>(x + (size_t)(bbase + row) * TT);
        float4 v = xg[c4];
        *reinterpret_cast<float4*>(&x_s[row * XS + c4 * 4]) = v;
    }
    for (int i = tid; i < 16 * HS; i += 256) { hb0[i] = 0; hb1[i] = 0; }

    // persistent B-fragments: W_hh rows for gates g = 64*t + n, bf16
    short8 bfr[4][2];
    float wih[4], bb[4];
    for (int t = 0; t < 4; ++t) {
        int g = 64 * t + n;
        wih[t] = W_ih[g];
        bb[t] = b_ih[g] + b_hh[g];
        for (int ks = 0; ks < 2; ++ks) {
            const float* wp = W_hh + g * 64 + ks * 32 + q * 8;
            short8 v;
            #pragma unroll
            for (int j = 0; j < 8; ++j) v[j] = (short)f2bf(wp[j]);
            bfr[t][ks] = v;
        }
    }

    float cst[2] = {0.f, 0.f};    // c-state, batch rows 2q+rr, hidden n
    float hvk[2] = {0.f, 0.f};    // last h, register-carried for the head

    floatx4 acc[4];               // slots r=2,3 face zero A-rows: init once, stay 0
    #pragma unroll
    for (int t = 0; t < 4; ++t) acc[t] = floatx4{0.f, 0.f, 0.f, 0.f};

    const int aoff = c * HS + q * 8;      // A-frag LDS offset (shorts)
    const int woff = (4 * q) * HS + n;    // h write base; +HS for rr=1
    const float* xrowA = &x_s[(2 * q) * XS];
    const float* xrowB = &x_s[(2 * q + 1) * XS];
    const float L1 = 1.44269504089f;      // log2(e)
    const float L2 = 2.88539008178f;      // 2*log2(e)

    __syncthreads();   // staging + zeroed h0 visible

    for (int ts4 = 0; ts4 < TT; ts4 += 4) {
        float4 xa = *reinterpret_cast<const float4*>(xrowA + ts4);
        float4 xb = *reinterpret_cast<const float4*>(xrowB + ts4);
        #pragma unroll
        for (int u = 0; u < 4; ++u) {
            const unsigned short* src = (u & 1) ? hb1 : hb0;
            unsigned short* dst = (u & 1) ? hb0 : hb1;

            short8 a0 = *reinterpret_cast<const short8*>(src + aoff);
            short8 a1 = *reinterpret_cast<const short8*>(src + aoff + 32);

            float x0 = (&xa.x)[u], x1 = (&xb.x)[u];
            #pragma unroll
            for (int t = 0; t < 4; ++t) {
                acc[t][0] = fmaf(x0, wih[t], bb[t]);
                acc[t][1] = fmaf(x1, wih[t], bb[t]);
            }

            #pragma unroll
            for (int t = 0; t < 4; ++t) {
                acc[t] = __builtin_amdgcn_mfma_f32_16x16x32_bf16(a0, bfr[t][0], acc[t], 0, 0, 0);
                acc[t] = __builtin_amdgcn_mfma_f32_16x16x32_bf16(a1, bfr[t][1], acc[t], 0, 0, 0);
            }

            #pragma unroll
            for (int rr = 0; rr < 2; ++rr) {
                float gi = acc[0][rr], gf = acc[1][rr], gg = acc[2][rr], go = acc[3][rr];
                float ei = __builtin_amdgcn_exp2f(-L1 * gi);
                float ef = __builtin_amdgcn_exp2f(-L1 * gf);
                float eg = __builtin_amdgcn_exp2f( L2 * gg);
                float eo = __builtin_amdgcn_exp2f(-L1 * go);
                float pf1 = 1.f + ef, pig = (1.f + ei) * (1.f + eg);
                float num = fmaf(cst[rr], pig, (eg - 1.f) * pf1);
                cst[rr] = num * __builtin_amdgcn_rcpf(pf1 * pig);
                float ec = __builtin_amdgcn_exp2f(L2 * cst[rr]);
                float hv = (ec - 1.f) * __builtin_amdgcn_rcpf((1.f + eo) * (1.f + ec));
                hvk[rr] = hv;
                dst[woff + rr * HS] = f2bf(hv);
            }
            __syncthreads();
        }
    }

    hf[(2 * q) * 65 + n] = hvk[0];
    hf[(2 * q + 1) * 65 + n] = hvk[1];
    __syncthreads();

    // head: out[b][o] = sum_n hf[b][n]*W_out[o][n] + b_out[o]
    if (tid < BT * 3) {
        int row = tid / 3, o = tid % 3;
        float s = b_out[o];
        #pragma unroll 8
        for (int k = 0; k < HH; ++k) s = fmaf(hf[row * 65 + k], W_out[o * 64 + k], s);
        out[(size_t)(bbase + row) * 3 + o] = s;
    }
}

extern "C" void kernel_launch(void* const* d_in, const int* in_sizes, int n_in,
                              void* d_out, int out_size, void* d_ws, size_t ws_size,
                              hipStream_t stream) {
    const float* x     = (const float*)d_in[0];
    const float* W_ih  = (const float*)d_in[1];
    const float* W_hh  = (const float*)d_in[2];
    const float* b_ih  = (const float*)d_in[3];
    const float* b_hh  = (const float*)d_in[4];
    const float* W_out = (const float*)d_in[5];
    const float* b_out = (const float*)d_in[6];
    float* out = (float*)d_out;
    hipLaunchKernelGGL(lstm_kernel, dim3(BATCH / BT), dim3(256), 0, stream,
                       x, W_ih, W_hh, b_ih, b_hh, W_out, b_out, out);
}